// Round 6
// baseline (122.078 us; speedup 1.0000x reference)
//
#include <hip/hip_runtime.h>
#include <hip/hip_bf16.h>

// GCN with DropEdge: out = A_norm @ (relu(A_norm @ (X@W0)) @ W1)
// A_norm = D^-1/2 (mask.A + I) D^-1/2
// N=50000, E=600000, D_IN=D_HID=128, D_OUT=64. fp32 in/out.
//
// Structure (round 6):
//  - padded adjacency (32 slots/row, Poisson(6) tail => P(overflow) ~ 3e-9),
//    built in ONE pass with atomicAdd rank; no scan, no scatter pass.
//  - dis = (1+deg)^-1/2 folded into stored operands: XWs = dis*X@W0,
//    HW1s = dis*(H@W1); SpMM needs no dis gathers.
//  - SpMMs process 2 rows per wave (half-wave per row) => half the VMEM
//    instructions, 2x memory-level parallelism.
//  - spmm1 fused with layer-2 GEMM (H tile only in LDS).

#define BLK 256
#define PADW 32

typedef __attribute__((ext_vector_type(8))) short short8v;
typedef __attribute__((ext_vector_type(8))) unsigned short ushort8v;
typedef __attribute__((ext_vector_type(4))) unsigned short ushort4v;
typedef __attribute__((ext_vector_type(4))) float float4v;

__device__ inline unsigned short f2b(float f) {
    __hip_bfloat16 h = __float2bfloat16(f);
    return *reinterpret_cast<unsigned short*>(&h);
}
__device__ inline float b2f(unsigned short u) {
    unsigned int v = (unsigned int)u << 16;
    return *reinterpret_cast<float*>(&v);
}
__device__ inline int clampi(int i, int k) {
    int j = i < k ? i : k - 1;
    return j < 0 ? 0 : j;
}

// ---- build: weight transpose->bf16 + padded adjacency in one pass ----------
__global__ __launch_bounds__(BLK) void buildK(const int* __restrict__ erow,
                                              const int* __restrict__ ecolin,
                                              const float* __restrict__ evals,
                                              const int* __restrict__ emask,
                                              const float* __restrict__ W0,
                                              const float* __restrict__ W1,
                                              unsigned short* __restrict__ W0T,
                                              unsigned short* __restrict__ W1T,
                                              int* __restrict__ counts,
                                              float* __restrict__ degext,
                                              int2* __restrict__ epack, int e) {
    int i = blockIdx.x * BLK + threadIdx.x;
    if (i < 128 * 128) {
        int c = i >> 7, k = i & 127;
        W0T[i] = f2b(W0[k * 128 + c]);
    } else if (i < 128 * 128 + 64 * 128) {
        int j = i - 128 * 128;
        int c = j >> 7, k = j & 127;
        W1T[j] = f2b(W1[k * 64 + c]);
    }
    if (i < e && emask[i]) {
        int r = erow[i], c = ecolin[i];
        float v = evals[i];
        int rank = atomicAdd(&counts[r], 1);
        atomicAdd(&degext[r], v);
        if (rank < PADW) epack[r * PADW + rank] = make_int2(c, __float_as_int(v));
    }
}

// ---- MFMA GEMM1: XWs[M,128](bf16) = dis(row) * (X[M,128](fp32) @ W0) ---------
// W0T = W0^T bf16 [128][128]. Block: 4 waves, 64 rows.
// LDS XOR swizzle (short-units: idx ^ ((row&7)<<3)) -> 2-way banks on b128 reads.
__global__ __launch_bounds__(BLK) void mgemm1K(const float* __restrict__ A,
                                               const unsigned short* __restrict__ WT,
                                               const float* __restrict__ degext,
                                               unsigned short* __restrict__ C, int M) {
    constexpr int NC = 128, NT = NC / 16;
    __shared__ __align__(16) unsigned short sA[64 * 128];
    __shared__ __align__(16) unsigned short sB[NC * 128];
    int t = threadIdx.x;
    int row0 = blockIdx.x * 64;

    for (int ch = t; ch < NC * 16; ch += BLK) {
        int row = ch >> 4, c16 = ch & 15;
        int dst = row * 128 + ((c16 * 8) ^ ((row & 7) << 3));
        *(ushort8v*)&sB[dst] = *(const ushort8v*)&WT[row * 128 + c16 * 8];
    }
    for (int q = t; q < 64 * 32; q += BLK) {
        int row = q >> 5, c4 = q & 31;
        int rg = row0 + row;
        float4 v = make_float4(0.f, 0.f, 0.f, 0.f);
        if (rg < M) v = *(const float4*)&A[(size_t)rg * 128 + c4 * 4];
        ushort4v b = {f2b(v.x), f2b(v.y), f2b(v.z), f2b(v.w)};
        int dst = row * 128 + ((c4 * 4) ^ ((row & 7) << 3));
        *(ushort4v*)&sA[dst] = b;
    }
    __syncthreads();

    int w = t >> 6, l = t & 63;
    int arow = w * 16 + (l & 15);
    int kgrp = l >> 4;
    int bcol = l & 15;
    float4v acc[NT];
#pragma unroll
    for (int nt = 0; nt < NT; nt++) acc[nt] = {0.f, 0.f, 0.f, 0.f};
#pragma unroll
    for (int ks = 0; ks < 4; ks++) {
        int koff = ks * 32 + kgrp * 8;
        short8v av = *(short8v*)&sA[arow * 128 + (koff ^ ((arow & 7) << 3))];
#pragma unroll
        for (int nt = 0; nt < NT; nt++) {
            int brow = nt * 16 + bcol;
            short8v bv = *(short8v*)&sB[brow * 128 + (koff ^ ((brow & 7) << 3))];
            acc[nt] = __builtin_amdgcn_mfma_f32_16x16x32_bf16(av, bv, acc[nt], 0, 0, 0);
        }
    }
    int crow0 = row0 + w * 16 + kgrp * 4;
    float dv[4];
#pragma unroll
    for (int j = 0; j < 4; j++) {
        int r = crow0 + j;
        dv[j] = (r < M) ? fminf(rsqrtf(1.0f + degext[r]), 10.0f) : 0.f;
    }
#pragma unroll
    for (int nt = 0; nt < NT; nt++) {
#pragma unroll
        for (int j = 0; j < 4; j++) {
            int r = crow0 + j;
            if (r < M) C[(size_t)r * NC + nt * 16 + bcol] = f2b(acc[nt][j] * dv[j]);
        }
    }
}

// ------ fused: H-tile = relu(dis*(XWs[r] + sum v*XWs[c])) in LDS; then
//        HW1s = dis * (H @ W1). 64 rows/block; wave handles 2 rows at a time
//        (lanes 0-31 row A, 32-63 row B; 4 dims/lane, dwordx2 gathers). -------
__global__ __launch_bounds__(BLK) void fuse1K(const unsigned short* __restrict__ XWs,
                                              const int* __restrict__ counts,
                                              const float* __restrict__ degext,
                                              const int2* __restrict__ epack,
                                              const unsigned short* __restrict__ W1T,
                                              unsigned short* __restrict__ HW1s, int n) {
    constexpr int NC = 64, NT = NC / 16;
    __shared__ __align__(16) unsigned short sA[64 * 128];
    __shared__ __align__(16) unsigned short sB[NC * 128];
    int t = threadIdx.x;
    int w = t >> 6, l = t & 63;
    int row0 = blockIdx.x * 64;

    for (int ch = t; ch < NC * 16; ch += BLK) {
        int row = ch >> 4, c16 = ch & 15;
        int dst = row * 128 + ((c16 * 8) ^ ((row & 7) << 3));
        *(ushort8v*)&sB[dst] = *(const ushort8v*)&W1T[row * 128 + c16 * 8];
    }

    int half = l >> 5, li = l & 31;
    int d0 = li * 4;  // ushort units: 4 dims/lane
    for (int p = 0; p < 8; p++) {
        int lrA = w * 16 + p, lrB = lrA + 8;
        int rA = row0 + lrA, rB = row0 + lrB;
        int kA = (rA < n) ? min(counts[rA], PADW) : 0;
        int kB = (rB < n) ? min(counts[rB], PADW) : 0;
        int kmax = max(kA, kB);
        int r_my = half ? rB : rA;
        bool valid = r_my < n;
        int rs = valid ? r_my : 0;
        int k_my = half ? kB : kA;

        float a0 = 0.f, a1 = 0.f, a2 = 0.f, a3 = 0.f;
        if (valid) {
            ushort4v sv = *(const ushort4v*)&XWs[(size_t)rs * 128 + d0];
            a0 = b2f(sv[0]); a1 = b2f(sv[1]); a2 = b2f(sv[2]); a3 = b2f(sv[3]);
        }
        long base = (long)rs * PADW;
        int i = 0;
        for (; i + 2 <= kmax; i += 2) {
            int2 e0 = epack[base + clampi(i, k_my)];
            int2 e1 = epack[base + clampi(i + 1, k_my)];
            int c0 = ((unsigned)e0.x < (unsigned)n) ? e0.x : 0;
            int c1 = ((unsigned)e1.x < (unsigned)n) ? e1.x : 0;
            float v0 = (i < k_my) ? __int_as_float(e0.y) : 0.f;
            float v1 = (i + 1 < k_my) ? __int_as_float(e1.y) : 0.f;
            ushort4v g0 = *(const ushort4v*)&XWs[(size_t)c0 * 128 + d0];
            ushort4v g1 = *(const ushort4v*)&XWs[(size_t)c1 * 128 + d0];
            a0 += v0 * b2f(g0[0]) + v1 * b2f(g1[0]);
            a1 += v0 * b2f(g0[1]) + v1 * b2f(g1[1]);
            a2 += v0 * b2f(g0[2]) + v1 * b2f(g1[2]);
            a3 += v0 * b2f(g0[3]) + v1 * b2f(g1[3]);
        }
        for (; i < kmax; i++) {
            int2 e0 = epack[base + clampi(i, k_my)];
            int c0 = ((unsigned)e0.x < (unsigned)n) ? e0.x : 0;
            float v0 = (i < k_my) ? __int_as_float(e0.y) : 0.f;
            ushort4v g0 = *(const ushort4v*)&XWs[(size_t)c0 * 128 + d0];
            a0 += v0 * b2f(g0[0]);
            a1 += v0 * b2f(g0[1]);
            a2 += v0 * b2f(g0[2]);
            a3 += v0 * b2f(g0[3]);
        }
        float disr = valid ? fminf(rsqrtf(1.0f + degext[rs]), 10.0f) : 0.f;
        a0 = fmaxf(a0, 0.f) * disr;
        a1 = fmaxf(a1, 0.f) * disr;
        a2 = fmaxf(a2, 0.f) * disr;
        a3 = fmaxf(a3, 0.f) * disr;
        int lr_my = half ? lrB : lrA;
        ushort4v hb = {f2b(a0), f2b(a1), f2b(a2), f2b(a3)};
        *(ushort4v*)&sA[lr_my * 128 + (d0 ^ ((lr_my & 7) << 3))] = hb;
    }
    __syncthreads();

    // GEMM phase: HW1s tile = dis * (sA @ W1)
    int arow = w * 16 + (l & 15);
    int kgrp = l >> 4;
    int bcol = l & 15;
    float4v acc[NT];
#pragma unroll
    for (int nt = 0; nt < NT; nt++) acc[nt] = {0.f, 0.f, 0.f, 0.f};
#pragma unroll
    for (int ks = 0; ks < 4; ks++) {
        int koff = ks * 32 + kgrp * 8;
        short8v av = *(short8v*)&sA[arow * 128 + (koff ^ ((arow & 7) << 3))];
#pragma unroll
        for (int nt = 0; nt < NT; nt++) {
            int brow = nt * 16 + bcol;
            short8v bv = *(short8v*)&sB[brow * 128 + (koff ^ ((brow & 7) << 3))];
            acc[nt] = __builtin_amdgcn_mfma_f32_16x16x32_bf16(av, bv, acc[nt], 0, 0, 0);
        }
    }
    int crow0 = blockIdx.x * 64 + w * 16 + kgrp * 4;
    float dv[4];
#pragma unroll
    for (int j = 0; j < 4; j++) {
        int r = crow0 + j;
        dv[j] = (r < n) ? fminf(rsqrtf(1.0f + degext[r]), 10.0f) : 0.f;
    }
#pragma unroll
    for (int nt = 0; nt < NT; nt++) {
#pragma unroll
        for (int j = 0; j < 4; j++) {
            int r = crow0 + j;
            if (r < n) HW1s[(size_t)r * NC + nt * 16 + bcol] = f2b(acc[nt][j] * dv[j]);
        }
    }
}

// ---- layer-2 SpMM: out[r] = dis[r]*(HW1s[r] + sum v*HW1s[c]), 2 rows/wave ----
__global__ __launch_bounds__(BLK) void spmm2K(const unsigned short* __restrict__ HW1s,
                                              const int* __restrict__ counts,
                                              const float* __restrict__ degext,
                                              const int2* __restrict__ epack,
                                              float* __restrict__ out, int n) {
    int gw = (blockIdx.x * BLK + threadIdx.x) >> 6;
    int l = threadIdx.x & 63;
    int half = l >> 5, li = l & 31;
    int rA = gw * 2, rB = gw * 2 + 1;
    if (rA >= n) return;
    int kA = min(counts[rA], PADW);
    int kB = (rB < n) ? min(counts[rB], PADW) : 0;
    int kmax = max(kA, kB);
    int r_my = half ? rB : rA;
    bool valid = r_my < n;
    int rs = valid ? r_my : 0;
    int k_my = half ? kB : kA;
    int d0 = li * 2;  // ushort units: 2 dims/lane

    float ax = 0.f, ay = 0.f;
    {
        unsigned int sv = *(const unsigned int*)&HW1s[(size_t)rs * 64 + d0];
        ax = b2f((unsigned short)sv);
        ay = b2f((unsigned short)(sv >> 16));
    }
    long base = (long)rs * PADW;
    int i = 0;
    for (; i + 2 <= kmax; i += 2) {
        int2 e0 = epack[base + clampi(i, k_my)];
        int2 e1 = epack[base + clampi(i + 1, k_my)];
        int c0 = ((unsigned)e0.x < (unsigned)n) ? e0.x : 0;
        int c1 = ((unsigned)e1.x < (unsigned)n) ? e1.x : 0;
        float v0 = (i < k_my) ? __int_as_float(e0.y) : 0.f;
        float v1 = (i + 1 < k_my) ? __int_as_float(e1.y) : 0.f;
        unsigned int g0 = *(const unsigned int*)&HW1s[(size_t)c0 * 64 + d0];
        unsigned int g1 = *(const unsigned int*)&HW1s[(size_t)c1 * 64 + d0];
        ax += v0 * b2f((unsigned short)g0) + v1 * b2f((unsigned short)g1);
        ay += v0 * b2f((unsigned short)(g0 >> 16)) + v1 * b2f((unsigned short)(g1 >> 16));
    }
    for (; i < kmax; i++) {
        int2 e0 = epack[base + clampi(i, k_my)];
        int c0 = ((unsigned)e0.x < (unsigned)n) ? e0.x : 0;
        float v0 = (i < k_my) ? __int_as_float(e0.y) : 0.f;
        unsigned int g0 = *(const unsigned int*)&HW1s[(size_t)c0 * 64 + d0];
        ax += v0 * b2f((unsigned short)g0);
        ay += v0 * b2f((unsigned short)(g0 >> 16));
    }
    if (valid) {
        float disr = fminf(rsqrtf(1.0f + degext[rs]), 10.0f);
        float2 o = make_float2(disr * ax, disr * ay);
        *(float2*)&out[(size_t)rs * 64 + d0] = o;
    }
}

// ---------------- launch ----------------

extern "C" void kernel_launch(void* const* d_in, const int* in_sizes, int n_in,
                              void* d_out, int out_size, void* d_ws, size_t ws_size,
                              hipStream_t stream) {
    const float* x = (const float*)d_in[0];
    const int* erow = (const int*)d_in[1];
    const int* ecolin = (const int*)d_in[2];
    const float* evals = (const float*)d_in[3];
    const int* emask = (const int*)d_in[4];     // bool canonicalized to int32
    const float* W0 = (const float*)d_in[5];
    const float* W1 = (const float*)d_in[6];
    float* out = (float*)d_out;

    const int n = in_sizes[0] / 128;   // 50000
    const int e = in_sizes[1];         // 600000

    char* ws = (char*)d_ws;
    size_t off = 0;
    auto alloc = [&](size_t bytes) {
        void* p = ws + off;
        off += (bytes + 255) & ~(size_t)255;
        return p;
    };
    int* counts = (int*)alloc((size_t)2 * n * 4);   // counts[n] + degext[n], one memset
    float* degext = (float*)(counts + n);
    int2* epack = (int2*)alloc((size_t)n * PADW * 8);
    unsigned short* W0T = (unsigned short*)alloc(128 * 128 * 2);
    unsigned short* W1T = (unsigned short*)alloc(64 * 128 * 2);
    unsigned short* XWs = (unsigned short*)alloc((size_t)n * 128 * 2);
    unsigned short* HW1s = (unsigned short*)alloc((size_t)n * 64 * 2);

    int nbE = (e + BLK - 1) / BLK;   // 2344
    int nbG = (n + 63) / 64;         // 782
    int nbS = (n / 2 + 3) / 4 + 1;   // spmm2: 2 rows/wave, 4 waves/block

    hipMemsetAsync(counts, 0, (size_t)2 * n * 4, stream);
    buildK<<<nbE, BLK, 0, stream>>>(erow, ecolin, evals, emask, W0, W1,
                                    W0T, W1T, counts, degext, epack, e);
    mgemm1K<<<nbG, BLK, 0, stream>>>(x, W0T, degext, XWs, n);
    fuse1K<<<nbG, BLK, 0, stream>>>(XWs, counts, degext, epack, W1T, HW1s, n);
    spmm2K<<<nbS, BLK, 0, stream>>>(HW1s, counts, degext, epack, out, n);
}

// Round 7
// 95.450 us; speedup vs baseline: 1.2790x; 1.2790x over previous
//
#include <hip/hip_runtime.h>
#include <hip/hip_bf16.h>

// GCN with DropEdge: out = A_norm @ (relu(A_norm @ (X@W0)) @ W1)
// A_norm = D^-1/2 (mask.A + I) D^-1/2
// N=50000, E=600000, D_IN=D_HID=128, D_OUT=64. fp32 in/out.
//
// Round 7: attack fuse1K's latency-boundness (46us, VALU 17%, HBM 10%).
//  - SpMM phase: 8-lane group per row -> 32 rows in flight per block
//    (was 8), 2 serial rows per group (was 8 pairs per wave).
//  - Block's edge tile staged to LDS first (16KB, coalesced stream);
//    per-edge chain is ds_read -> gather instead of global -> global.
//  - Fixed unroll-4 with clamped slot index -> 8 b128 gathers in flight.
//  - spmm2: 16-lane group per row, unroll-4 clamped, 3125 blocks.

#define BLK 256
#define PADW 32

typedef __attribute__((ext_vector_type(8))) short short8v;
typedef __attribute__((ext_vector_type(8))) unsigned short ushort8v;
typedef __attribute__((ext_vector_type(4))) unsigned short ushort4v;
typedef __attribute__((ext_vector_type(4))) float float4v;

__device__ inline unsigned short f2b(float f) {
    __hip_bfloat16 h = __float2bfloat16(f);
    return *reinterpret_cast<unsigned short*>(&h);
}
__device__ inline float b2f(unsigned short u) {
    unsigned int v = (unsigned int)u << 16;
    return *reinterpret_cast<float*>(&v);
}

// ---- build: weight transpose->bf16 + padded adjacency in one pass ----------
__global__ __launch_bounds__(BLK) void buildK(const int* __restrict__ erow,
                                              const int* __restrict__ ecolin,
                                              const float* __restrict__ evals,
                                              const int* __restrict__ emask,
                                              const float* __restrict__ W0,
                                              const float* __restrict__ W1,
                                              unsigned short* __restrict__ W0T,
                                              unsigned short* __restrict__ W1T,
                                              int* __restrict__ counts,
                                              float* __restrict__ degext,
                                              int2* __restrict__ epack, int e) {
    int i = blockIdx.x * BLK + threadIdx.x;
    if (i < 128 * 128) {
        int c = i >> 7, k = i & 127;
        W0T[i] = f2b(W0[k * 128 + c]);
    } else if (i < 128 * 128 + 64 * 128) {
        int j = i - 128 * 128;
        int c = j >> 7, k = j & 127;
        W1T[j] = f2b(W1[k * 64 + c]);
    }
    if (i < e && emask[i]) {
        int r = erow[i], c = ecolin[i];
        float v = evals[i];
        int rank = atomicAdd(&counts[r], 1);
        atomicAdd(&degext[r], v);
        if (rank < PADW) epack[r * PADW + rank] = make_int2(c, __float_as_int(v));
    }
}

// ---- MFMA GEMM1: XWs[M,128](bf16) = dis(row) * (X[M,128](fp32) @ W0) ---------
__global__ __launch_bounds__(BLK) void mgemm1K(const float* __restrict__ A,
                                               const unsigned short* __restrict__ WT,
                                               const float* __restrict__ degext,
                                               unsigned short* __restrict__ C, int M) {
    constexpr int NC = 128, NT = NC / 16;
    __shared__ __align__(16) unsigned short sA[64 * 128];
    __shared__ __align__(16) unsigned short sB[NC * 128];
    int t = threadIdx.x;
    int row0 = blockIdx.x * 64;

    for (int ch = t; ch < NC * 16; ch += BLK) {
        int row = ch >> 4, c16 = ch & 15;
        int dst = row * 128 + ((c16 * 8) ^ ((row & 7) << 3));
        *(ushort8v*)&sB[dst] = *(const ushort8v*)&WT[row * 128 + c16 * 8];
    }
    for (int q = t; q < 64 * 32; q += BLK) {
        int row = q >> 5, c4 = q & 31;
        int rg = row0 + row;
        float4 v = make_float4(0.f, 0.f, 0.f, 0.f);
        if (rg < M) v = *(const float4*)&A[(size_t)rg * 128 + c4 * 4];
        ushort4v b = {f2b(v.x), f2b(v.y), f2b(v.z), f2b(v.w)};
        int dst = row * 128 + ((c4 * 4) ^ ((row & 7) << 3));
        *(ushort4v*)&sA[dst] = b;
    }
    __syncthreads();

    int w = t >> 6, l = t & 63;
    int arow = w * 16 + (l & 15);
    int kgrp = l >> 4;
    int bcol = l & 15;
    float4v acc[NT];
#pragma unroll
    for (int nt = 0; nt < NT; nt++) acc[nt] = {0.f, 0.f, 0.f, 0.f};
#pragma unroll
    for (int ks = 0; ks < 4; ks++) {
        int koff = ks * 32 + kgrp * 8;
        short8v av = *(short8v*)&sA[arow * 128 + (koff ^ ((arow & 7) << 3))];
#pragma unroll
        for (int nt = 0; nt < NT; nt++) {
            int brow = nt * 16 + bcol;
            short8v bv = *(short8v*)&sB[brow * 128 + (koff ^ ((brow & 7) << 3))];
            acc[nt] = __builtin_amdgcn_mfma_f32_16x16x32_bf16(av, bv, acc[nt], 0, 0, 0);
        }
    }
    int crow0 = row0 + w * 16 + kgrp * 4;
    float dv[4];
#pragma unroll
    for (int j = 0; j < 4; j++) {
        int r = crow0 + j;
        dv[j] = (r < M) ? fminf(rsqrtf(1.0f + degext[r]), 10.0f) : 0.f;
    }
#pragma unroll
    for (int nt = 0; nt < NT; nt++) {
#pragma unroll
        for (int j = 0; j < 4; j++) {
            int r = crow0 + j;
            if (r < M) C[(size_t)r * NC + nt * 16 + bcol] = f2b(acc[nt][j] * dv[j]);
        }
    }
}

// ------ fused: H-tile = relu(dis*(XWs[r] + sum v*XWs[c])) in LDS; then
//        HW1s = dis * (H @ W1).
//   SpMM phase: 8-lane group per row (32 rows in flight), edge tile in LDS,
//   unroll-4 clamped => 8 b128 gathers outstanding per lane.
__global__ __launch_bounds__(BLK) void fuse1K(const unsigned short* __restrict__ XWs,
                                              const int* __restrict__ counts,
                                              const float* __restrict__ degext,
                                              const int2* __restrict__ epack,
                                              const unsigned short* __restrict__ W1T,
                                              unsigned short* __restrict__ HW1s, int n) {
    constexpr int NC = 64, NT = NC / 16;
    __shared__ __align__(16) unsigned short sA[64 * 128];
    __shared__ __align__(16) unsigned short sB[NC * 128];
    __shared__ __align__(16) int2 sE[64 * PADW];
    __shared__ int sK[64];
    __shared__ float sD[64];
    int t = threadIdx.x;
    int row0 = blockIdx.x * 64;

    // stage W1T (swizzled)
    for (int ch = t; ch < NC * 16; ch += BLK) {
        int row = ch >> 4, c16 = ch & 15;
        int dst = row * 128 + ((c16 * 8) ^ ((row & 7) << 3));
        *(ushort8v*)&sB[dst] = *(const ushort8v*)&W1T[row * 128 + c16 * 8];
    }
    // stage edge tile: 64 rows x 32 slots x 8B = 16KB contiguous stream
    {
        const int4* esrc = (const int4*)(epack + (size_t)row0 * PADW);
        int4* edst = (int4*)sE;
#pragma unroll
        for (int i = 0; i < 4; i++) edst[t + i * BLK] = esrc[t + i * BLK];
    }
    if (t < 64) {
        int r = row0 + t;
        sK[t] = (r < n) ? min(counts[r], PADW) : 0;
        sD[t] = (r < n) ? fminf(rsqrtf(1.0f + degext[r]), 10.0f) : 0.f;
    }
    __syncthreads();

    // SpMM phase: group g (8 lanes) handles rows lr = g*2, g*2+1
    int g = t >> 3, li = t & 7;
    int d0 = li * 16;  // ushort units, 16 dims/lane
    for (int p = 0; p < 2; p++) {
        int lr = g * 2 + p;
        int r = row0 + lr;
        int k = sK[lr];
        float acc[16];
        if (r < n) {
            ushort8v s0 = *(const ushort8v*)&XWs[(size_t)r * 128 + d0];
            ushort8v s1 = *(const ushort8v*)&XWs[(size_t)r * 128 + d0 + 8];
#pragma unroll
            for (int q = 0; q < 8; q++) { acc[q] = b2f(s0[q]); acc[8 + q] = b2f(s1[q]); }
        } else {
#pragma unroll
            for (int q = 0; q < 16; q++) acc[q] = 0.f;
        }
        const int2* erow_lds = &sE[lr * PADW];
        for (int i = 0; i < k; i += 4) {
            int i1 = i + 1 < k ? i + 1 : k - 1;
            int i2 = i + 2 < k ? i + 2 : k - 1;
            int i3 = i + 3 < k ? i + 3 : k - 1;
            int2 e0 = erow_lds[i], e1 = erow_lds[i1], e2 = erow_lds[i2], e3 = erow_lds[i3];
            float v0 = __int_as_float(e0.y);
            float v1 = (i + 1 < k) ? __int_as_float(e1.y) : 0.f;
            float v2 = (i + 2 < k) ? __int_as_float(e2.y) : 0.f;
            float v3 = (i + 3 < k) ? __int_as_float(e3.y) : 0.f;
            ushort8v ga0 = *(const ushort8v*)&XWs[(size_t)e0.x * 128 + d0];
            ushort8v gb0 = *(const ushort8v*)&XWs[(size_t)e0.x * 128 + d0 + 8];
            ushort8v ga1 = *(const ushort8v*)&XWs[(size_t)e1.x * 128 + d0];
            ushort8v gb1 = *(const ushort8v*)&XWs[(size_t)e1.x * 128 + d0 + 8];
            ushort8v ga2 = *(const ushort8v*)&XWs[(size_t)e2.x * 128 + d0];
            ushort8v gb2 = *(const ushort8v*)&XWs[(size_t)e2.x * 128 + d0 + 8];
            ushort8v ga3 = *(const ushort8v*)&XWs[(size_t)e3.x * 128 + d0];
            ushort8v gb3 = *(const ushort8v*)&XWs[(size_t)e3.x * 128 + d0 + 8];
#pragma unroll
            for (int q = 0; q < 8; q++) {
                acc[q]     += v0 * b2f(ga0[q]) + v1 * b2f(ga1[q])
                            + v2 * b2f(ga2[q]) + v3 * b2f(ga3[q]);
                acc[8 + q] += v0 * b2f(gb0[q]) + v1 * b2f(gb1[q])
                            + v2 * b2f(gb2[q]) + v3 * b2f(gb3[q]);
            }
        }
        float dis = sD[lr];
        ushort8v h0, h1;
#pragma unroll
        for (int q = 0; q < 8; q++) {
            h0[q] = f2b(fmaxf(acc[q], 0.f) * dis);
            h1[q] = f2b(fmaxf(acc[8 + q], 0.f) * dis);
        }
        int sw = (lr & 7) << 3;
        *(ushort8v*)&sA[lr * 128 + (d0 ^ sw)] = h0;
        *(ushort8v*)&sA[lr * 128 + ((d0 + 8) ^ sw)] = h1;
    }
    __syncthreads();

    // GEMM phase: HW1s tile = dis * (sA @ W1)
    int w = t >> 6, l = t & 63;
    int arow = w * 16 + (l & 15);
    int kgrp = l >> 4;
    int bcol = l & 15;
    float4v acc2[NT];
#pragma unroll
    for (int nt = 0; nt < NT; nt++) acc2[nt] = {0.f, 0.f, 0.f, 0.f};
#pragma unroll
    for (int ks = 0; ks < 4; ks++) {
        int koff = ks * 32 + kgrp * 8;
        short8v av = *(short8v*)&sA[arow * 128 + (koff ^ ((arow & 7) << 3))];
#pragma unroll
        for (int nt = 0; nt < NT; nt++) {
            int brow = nt * 16 + bcol;
            short8v bv = *(short8v*)&sB[brow * 128 + (koff ^ ((brow & 7) << 3))];
            acc2[nt] = __builtin_amdgcn_mfma_f32_16x16x32_bf16(av, bv, acc2[nt], 0, 0, 0);
        }
    }
    int lrow0 = w * 16 + kgrp * 4;
#pragma unroll
    for (int nt = 0; nt < NT; nt++) {
#pragma unroll
        for (int j = 0; j < 4; j++) {
            int r = row0 + lrow0 + j;
            if (r < n) HW1s[(size_t)r * NC + nt * 16 + bcol] = f2b(acc2[nt][j] * sD[lrow0 + j]);
        }
    }
}

// ---- layer-2 SpMM: 16-lane group per row (4 rows/wave), unroll-4 clamped ----
__global__ __launch_bounds__(BLK) void spmm2K(const unsigned short* __restrict__ HW1s,
                                              const int* __restrict__ counts,
                                              const float* __restrict__ degext,
                                              const int2* __restrict__ epack,
                                              float* __restrict__ out, int n) {
    int t = threadIdx.x;
    int r = blockIdx.x * 16 + (t >> 4);
    int li = t & 15;
    if (r >= n) return;
    int k = min(counts[r], PADW);
    int d0 = li * 4;  // ushort units, 4 dims/lane
    float a0, a1, a2, a3;
    {
        ushort4v sv = *(const ushort4v*)&HW1s[(size_t)r * 64 + d0];
        a0 = b2f(sv[0]); a1 = b2f(sv[1]); a2 = b2f(sv[2]); a3 = b2f(sv[3]);
    }
    const int2* eb = epack + (size_t)r * PADW;
    for (int i = 0; i < k; i += 4) {
        int i1 = i + 1 < k ? i + 1 : k - 1;
        int i2 = i + 2 < k ? i + 2 : k - 1;
        int i3 = i + 3 < k ? i + 3 : k - 1;
        int2 e0 = eb[i], e1 = eb[i1], e2 = eb[i2], e3 = eb[i3];
        float v0 = __int_as_float(e0.y);
        float v1 = (i + 1 < k) ? __int_as_float(e1.y) : 0.f;
        float v2 = (i + 2 < k) ? __int_as_float(e2.y) : 0.f;
        float v3 = (i + 3 < k) ? __int_as_float(e3.y) : 0.f;
        ushort4v g0 = *(const ushort4v*)&HW1s[(size_t)e0.x * 64 + d0];
        ushort4v g1 = *(const ushort4v*)&HW1s[(size_t)e1.x * 64 + d0];
        ushort4v g2 = *(const ushort4v*)&HW1s[(size_t)e2.x * 64 + d0];
        ushort4v g3 = *(const ushort4v*)&HW1s[(size_t)e3.x * 64 + d0];
        a0 += v0 * b2f(g0[0]) + v1 * b2f(g1[0]) + v2 * b2f(g2[0]) + v3 * b2f(g3[0]);
        a1 += v0 * b2f(g0[1]) + v1 * b2f(g1[1]) + v2 * b2f(g2[1]) + v3 * b2f(g3[1]);
        a2 += v0 * b2f(g0[2]) + v1 * b2f(g1[2]) + v2 * b2f(g2[2]) + v3 * b2f(g3[2]);
        a3 += v0 * b2f(g0[3]) + v1 * b2f(g1[3]) + v2 * b2f(g2[3]) + v3 * b2f(g3[3]);
    }
    float dis = fminf(rsqrtf(1.0f + degext[r]), 10.0f);
    float4 o = make_float4(a0 * dis, a1 * dis, a2 * dis, a3 * dis);
    *(float4*)&out[(size_t)r * 64 + li * 4] = o;
}

// ---------------- launch ----------------

extern "C" void kernel_launch(void* const* d_in, const int* in_sizes, int n_in,
                              void* d_out, int out_size, void* d_ws, size_t ws_size,
                              hipStream_t stream) {
    const float* x = (const float*)d_in[0];
    const int* erow = (const int*)d_in[1];
    const int* ecolin = (const int*)d_in[2];
    const float* evals = (const float*)d_in[3];
    const int* emask = (const int*)d_in[4];     // bool canonicalized to int32
    const float* W0 = (const float*)d_in[5];
    const float* W1 = (const float*)d_in[6];
    float* out = (float*)d_out;

    const int n = in_sizes[0] / 128;   // 50000
    const int e = in_sizes[1];         // 600000

    char* ws = (char*)d_ws;
    size_t off = 0;
    auto alloc = [&](size_t bytes) {
        void* p = ws + off;
        off += (bytes + 255) & ~(size_t)255;
        return p;
    };
    int* counts = (int*)alloc((size_t)2 * n * 4);   // counts[n] + degext[n], one memset
    float* degext = (float*)(counts + n);
    int2* epack = (int2*)alloc((size_t)n * PADW * 8);
    unsigned short* W0T = (unsigned short*)alloc(128 * 128 * 2);
    unsigned short* W1T = (unsigned short*)alloc(64 * 128 * 2);
    unsigned short* XWs = (unsigned short*)alloc((size_t)n * 128 * 2);
    unsigned short* HW1s = (unsigned short*)alloc((size_t)n * 64 * 2);

    int nbE = (e + BLK - 1) / BLK;   // 2344
    int nbG = (n + 63) / 64;         // 782
    int nbS = (n + 15) / 16;         // 3125

    hipMemsetAsync(counts, 0, (size_t)2 * n * 4, stream);
    buildK<<<nbE, BLK, 0, stream>>>(erow, ecolin, evals, emask, W0, W1,
                                    W0T, W1T, counts, degext, epack, e);
    mgemm1K<<<nbG, BLK, 0, stream>>>(x, W0T, degext, XWs, n);
    fuse1K<<<nbG, BLK, 0, stream>>>(XWs, counts, degext, epack, W1T, HW1s, n);
    spmm2K<<<nbS, BLK, 0, stream>>>(HW1s, counts, degext, epack, out, n);
}